// Round 10
// baseline (269.026 us; speedup 1.0000x reference)
//
#include <hip/hip_runtime.h>
#include <hip/hip_bf16.h>
#include <cstdint>

#define B_  4
#define S_  2048
#define H_  1024
#define NH_ 16
#define HD_ 64

using short8  = __attribute__((ext_vector_type(8))) short;
using floatx4 = __attribute__((ext_vector_type(4))) float;

__device__ __forceinline__ unsigned short f2b(float f) {
  union { float f; unsigned int u; } x; x.f = f;
  unsigned int r = x.u + 0x7fffu + ((x.u >> 16) & 1u);
  return (unsigned short)(r >> 16);
}
__device__ __forceinline__ unsigned int pack2(float a, float b) {
  return (unsigned int)f2b(a) | ((unsigned int)f2b(b) << 16);
}
// single-instruction packed f32x2 -> bf16x2 (RNE). gfx950 VOP3; no builtin.
__device__ __forceinline__ unsigned int cvt_pk_bf16(float lo, float hi) {
  unsigned int r;
  asm("v_cvt_pk_bf16_f32 %0, %1, %2" : "=v"(r) : "v"(lo), "v"(hi));
  return r;
}

// async global->LDS, 16B per lane. lds dest = wave-uniform base + lane*16.
__device__ __forceinline__ void async16(void* lds, const void* g) {
  __builtin_amdgcn_global_load_lds(
      (const __attribute__((address_space(1))) unsigned int*)g,
      (__attribute__((address_space(3))) unsigned int*)lds, 16, 0, 0);
}

// ---------- merged prologue: cast x + transpose both weights ----------
// qk_scale: fold attn's 1/sqrt(HD)=0.125 into Q weight columns (c<1024).
// Exact power-of-2 scale -> bf16 exponent shift only -> bit-identical attn.
__device__ __forceinline__ void transpose_tile(const float* __restrict__ in,
                                               unsigned short* __restrict__ out,
                                               int R, int C, int c0, int r0,
                                               bool qk_scale) {
  __shared__ float tile[32][33];
  int tx = threadIdx.x & 31, ty = threadIdx.x >> 5;  // 32 x 8
  for (int i = 0; i < 4; i++) {
    int r = r0 + ty + i * 8;
    tile[ty + i * 8][tx] = in[(size_t)r * C + c0 + tx];
  }
  __syncthreads();
  for (int i = 0; i < 4; i++) {
    int c = c0 + ty + i * 8;
    float s = (qk_scale && c < 1024) ? 0.125f : 1.0f;
    out[(size_t)c * R + r0 + tx] = f2b(tile[tx][ty + i * 8] * s);
  }
}

__global__ void k_prep(const float* __restrict__ x, const float* __restrict__ w_qkv,
                       const float* __restrict__ w_out,
                       unsigned short* __restrict__ xb, unsigned short* __restrict__ wqkvT,
                       unsigned short* __restrict__ woutT) {
  int bx = blockIdx.x;
  if (bx < 8192) {                       // cast x: 8192 blocks * 256 thr * 4 elems
    int i = (bx * 256 + threadIdx.x) * 4;
    float4 v = *(const float4*)(x + i);
    ushort4 o;
    o.x = f2b(v.x); o.y = f2b(v.y); o.z = f2b(v.z); o.w = f2b(v.w);
    *(ushort4*)(xb + i) = o;
  } else if (bx < 8192 + 3072) {         // w_qkv [1024][3072] -> [3072][1024]
    int t = bx - 8192;
    transpose_tile(w_qkv, wqkvT, H_, 3 * H_, (t % 96) * 32, (t / 96) * 32, true);
  } else {                               // w_out [1024][1024] -> [1024][1024]^T
    int t = bx - 8192 - 3072;
    transpose_tile(w_out, woutT, H_, H_, (t & 31) * 32, (t >> 5) * 32, false);
  }
}

// ---------- GEMM: 128x128 tile, BK=64, double-buffered (64 KB LDS) ----------
// Verified rounds 5/6: 81.5 -> 69.2 us vs BK=32 (halves barrier+drain events).
template <bool OUT_BF16>
__global__ __launch_bounds__(256, 2) void k_gemm_bt64(
    const unsigned short* __restrict__ A,   // [M][K] bf16
    const unsigned short* __restrict__ BT,  // [N][K] bf16
    const float* __restrict__ bias,         // [N]
    void* __restrict__ Cout,
    unsigned short* __restrict__ vt,        // V-transposed out (OUT_BF16 only)
    int M, int N, int K) {
  __shared__ __align__(16) unsigned short As[2][128 * 64];
  __shared__ __align__(16) unsigned short Bs[2][128 * 64];
  const int tid  = threadIdx.x;
  const int lane = tid & 63, wave = tid >> 6;
  const int quad = lane >> 4, l16 = lane & 15;
  const int wm = wave >> 1, wn = wave & 1;
  const int m0 = blockIdx.y * 128, n0 = blockIdx.x * 128;

  floatx4 acc[4][4];
#pragma unroll
  for (int mt = 0; mt < 4; mt++)
#pragma unroll
    for (int nt = 0; nt < 4; nt++)
      acc[mt][nt] = (floatx4){0.f, 0.f, 0.f, 0.f};

  // 1024 chunks (16B) per array: row = c>>3 (128 rows), slot = c&7,
  // pre-swizzled global source c8 = slot ^ (row&7).
  auto stage = [&](int k0, int bufi) {
#pragma unroll
    for (int j = 0; j < 4; j++) {
      int c = j * 256 + tid;
      int row = c >> 3, c8 = (c & 7) ^ (row & 7);
      async16(&As[bufi][c * 8], &A[(size_t)(m0 + row) * K + k0 + c8 * 8]);
    }
#pragma unroll
    for (int j = 0; j < 4; j++) {
      int c = j * 256 + tid;
      int row = c >> 3, c8 = (c & 7) ^ (row & 7);
      async16(&Bs[bufi][c * 8], &BT[(size_t)(n0 + row) * K + k0 + c8 * 8]);
    }
  };

  stage(0, 0);
  int it = 0;
  for (int k0 = 0; k0 < K; k0 += 64, it++) {
    const int cur = it & 1;
    __syncthreads();                          // buf[cur] ready (barrier drains vmcnt)
    if (k0 + 64 < K) stage(k0 + 64, cur ^ 1); // prefetch, drained at NEXT barrier
    short8 af[4][2], bq[4][2];
#pragma unroll
    for (int t = 0; t < 4; t++) {
      int ra = wm * 64 + t * 16 + l16;
      int rb = wn * 64 + t * 16 + l16;
#pragma unroll
      for (int ks = 0; ks < 2; ks++) {
        af[t][ks] = *(const short8*)&As[cur][(ra * 8 + ((ks * 4 + quad) ^ (ra & 7))) * 8];
        bq[t][ks] = *(const short8*)&Bs[cur][(rb * 8 + ((ks * 4 + quad) ^ (rb & 7))) * 8];
      }
    }
#pragma unroll
    for (int ks = 0; ks < 2; ks++)
#pragma unroll
      for (int mt = 0; mt < 4; mt++)
#pragma unroll
        for (int nt = 0; nt < 4; nt++)
          acc[mt][nt] = __builtin_amdgcn_mfma_f32_16x16x32_bf16(af[mt][ks], bq[nt][ks], acc[mt][nt], 0, 0, 0);
  }

  if (OUT_BF16 && n0 >= 2048) {
#pragma unroll
    for (int mt = 0; mt < 4; mt++) {
      int row0 = m0 + wm * 64 + mt * 16 + quad * 4;
      int b = row0 >> 11, s = row0 & 2047;
#pragma unroll
      for (int nt = 0; nt < 4; nt++) {
        int col = n0 + wn * 64 + nt * 16 + l16;
        float bv = bias[col];
        uint2 u;
        u.x = pack2(acc[mt][nt][0] + bv, acc[mt][nt][1] + bv);
        u.y = pack2(acc[mt][nt][2] + bv, acc[mt][nt][3] + bv);
        *(uint2*)&vt[(size_t)(b * 1024 + (col - 2048)) * S_ + s] = u;
      }
    }
  } else {
#pragma unroll
    for (int mt = 0; mt < 4; mt++) {
      int row = m0 + wm * 64 + mt * 16 + quad * 4;
#pragma unroll
      for (int nt = 0; nt < 4; nt++) {
        int col = n0 + wn * 64 + nt * 16 + l16;
        float bv = bias[col];
        if (OUT_BF16 && col < 1024) bv *= 0.125f;   // Q bias follows the Q-weight scale
#pragma unroll
        for (int r = 0; r < 4; r++) {
          float v = acc[mt][nt][r] + bv;
          if (OUT_BF16) ((unsigned short*)Cout)[(size_t)(row + r) * N + col] = f2b(v);
          else          ((float*)Cout)[(size_t)(row + r) * N + col] = v;
        }
      }
    }
  }
}

// ---------- flash attention (causal), S^T layout, 40 KB LDS ----------
// Q pre-scaled by 0.125 in the weights -> exp(z) directly.
// Round-10: (a) Ps reverted to single 2KB/wave buffer (round-9's per-g split
// pushed LDS 40->48KB -> 3 blocks/CU instead of 4; occupancy loss ate the
// latency win). (b) P packing via v_cvt_pk_bf16_f32: 2 ops/uint2 instead of
// ~10 (4 f2b_fast + or/shl) -- pure VALU cut on the VALU-bound kernel
// (VALUBusy 51% vs MfmaUtil 21%), no structure/occupancy change.
__global__ __launch_bounds__(256, 3) void k_attn(
    const unsigned short* __restrict__ qkv,  // [B*S][3H] bf16 (Q,K valid)
    const unsigned short* __restrict__ vt,   // [B*NH*HD][S] bf16
    unsigned short* __restrict__ outb) {     // [B*S][H] bf16
  __shared__ __align__(16) unsigned short Ks [2][64 * 64];  // [kv][hd] swizzled
  __shared__ __align__(16) unsigned short VTs[2][64 * 64];  // [hd][kv] swizzled
  __shared__ __align__(16) unsigned short Ps[4][16 * 64];   // per-wave [q][kv] swizzled

  const int tid  = threadIdx.x;
  const int lane = tid & 63, w = tid >> 6;
  const int quad = lane >> 4, l16 = lane & 15;
  const int qt = (S_ / 128 - 1) - (blockIdx.x >> 6);  // long blocks dispatch first
  const int bh = blockIdx.x & 63;
  const int b = bh >> 4, h = bh & 15;
  const int qwv = qt * 128 + w * 32;
  const int wv2 = w & 1;

  // Q B-fragments (S^T = K * Q^T): B[k=d][n=q], lane n=l16, k=quad*8+j
  short8 qf[2][2];
  for (int g = 0; g < 2; g++)
    for (int kh = 0; kh < 2; kh++)
      qf[g][kh] = *(const short8*)&qkv[(size_t)(b * S_ + qwv + g * 16 + l16) * (3 * H_)
                                       + h * HD_ + kh * 32 + quad * 8];

  floatx4 oacc[2][4];
  float lsum[2] = {0.f, 0.f};
  for (int g = 0; g < 2; g++)
    for (int ct = 0; ct < 4; ct++) oacc[g][ct] = (floatx4){0.f, 0.f, 0.f, 0.f};

  auto stage = [&](int kt, int bufi) {
    if (w < 2) {
      for (int j = 0; j < 4; j++) {
        int c = wv2 * 256 + j * 64 + lane;  // 0..511
        int row = c >> 3, c8 = (c & 7) ^ (row & 7);
        async16(&Ks[bufi][c * 8],
                &qkv[(size_t)(b * S_ + kt * 64 + row) * (3 * H_) + H_ + h * HD_ + c8 * 8]);
      }
    } else {
      for (int j = 0; j < 4; j++) {
        int c = wv2 * 256 + j * 64 + lane;
        int row = c >> 3, c8 = (c & 7) ^ (row & 7);
        async16(&VTs[bufi][c * 8],
                &vt[(size_t)(bh * HD_ + row) * S_ + kt * 64 + c8 * 8]);
      }
    }
  };

  unsigned short* Pw = &Ps[w][0];

  const int ktmax = 2 * qt + 1;
  stage(0, 0);
  for (int kt = 0; kt <= ktmax; kt++) {
    const int cur = kt & 1;
    __syncthreads();                          // buf[cur] visible; prev reads done
    if (kt < ktmax) stage(kt + 1, cur ^ 1);   // prefetch, hidden behind compute

    if (kt * 64 <= qwv + 31) {
      const bool need_mask = (kt * 64 + 63 > qwv);

      // V A-fragments: A[m=d][k=kv]
      short8 vf[4][2];
      for (int ct = 0; ct < 4; ct++)
        for (int kh = 0; kh < 2; kh++) {
          int vrow = ct * 16 + l16;
          vf[ct][kh] = *(const short8*)&VTs[cur][(vrow * 8 + ((kh * 4 + quad) ^ (vrow & 7))) * 8];
        }

      // S^T = K Q^T -> p (packed into regs)
      uint2 pk[2][4];
      for (int ct = 0; ct < 4; ct++) {
        int krow = ct * 16 + l16;
        short8 kf0 = *(const short8*)&Ks[cur][(krow * 8 + ((0 + quad) ^ (krow & 7))) * 8];
        short8 kf1 = *(const short8*)&Ks[cur][(krow * 8 + ((4 + quad) ^ (krow & 7))) * 8];
        for (int g = 0; g < 2; g++) {
          floatx4 z = (floatx4){0.f, 0.f, 0.f, 0.f};
          z = __builtin_amdgcn_mfma_f32_16x16x32_bf16(kf0, qf[g][0], z, 0, 0, 0);
          z = __builtin_amdgcn_mfma_f32_16x16x32_bf16(kf1, qf[g][1], z, 0, 0, 0);
          // lane: q = qwv+g*16+l16 fixed; kv = kt*64+ct*16+quad*4+r
          float p[4];
          if (need_mask) {
            int kvb = kt * 64 + ct * 16 + quad * 4;
            int q = qwv + g * 16 + l16;
            for (int r = 0; r < 4; r++)
              p[r] = (kvb + r <= q) ? __expf(z[r]) : 0.f;
          } else {
            for (int r = 0; r < 4; r++) p[r] = __expf(z[r]);
          }
          lsum[g] += (p[0] + p[1]) + (p[2] + p[3]);
          pk[g][ct].x = cvt_pk_bf16(p[0], p[1]);
          pk[g][ct].y = cvt_pk_bf16(p[2], p[3]);
        }
      }

      // per-g: P round-trip through 2 KB swizzled buffer, then PV MFMAs.
      // (DS ops in-order per wave -> WAR-safe reuse across g)
      for (int g = 0; g < 2; g++) {
        for (int ct = 0; ct < 4; ct++) {
          int slot = (ct * 2 + (quad >> 1)) ^ (l16 & 7);
          *(uint2*)&Pw[l16 * 64 + slot * 8 + (quad & 1) * 4] = pk[g][ct];
        }
        for (int kh = 0; kh < 2; kh++) {
          short8 pf = *(const short8*)&Pw[l16 * 64 + ((kh * 4 + quad) ^ (l16 & 7)) * 8];
          for (int ct = 0; ct < 4; ct++)
            oacc[g][ct] = __builtin_amdgcn_mfma_f32_16x16x32_bf16(vf[ct][kh], pf, oacc[g][ct], 0, 0, 0);
        }
      }
    }
  }

  // finish row sums: reduce across quads (lanes sharing l16 share q)
  for (int g = 0; g < 2; g++) {
    lsum[g] += __shfl_xor(lsum[g], 16);
    lsum[g] += __shfl_xor(lsum[g], 32);
  }

  // epilogue: lane holds q=l16 fixed, d=ct*16+quad*4+r -> packed 8B stores
  for (int g = 0; g < 2; g++) {
    float inv = 1.0f / lsum[g];
    int q = qwv + g * 16 + l16;
    for (int ct = 0; ct < 4; ct++) {
      uint2 u;
      u.x = pack2(oacc[g][ct][0] * inv, oacc[g][ct][1] * inv);
      u.y = pack2(oacc[g][ct][2] * inv, oacc[g][ct][3] * inv);
      *(uint2*)&outb[(size_t)(b * S_ + q) * H_ + h * HD_ + ct * 16 + quad * 4] = u;
    }
  }
}

extern "C" void kernel_launch(void* const* d_in, const int* in_sizes, int n_in,
                              void* d_out, int out_size, void* d_ws, size_t ws_size,
                              hipStream_t stream) {
  const float* x     = (const float*)d_in[0];
  const float* w_qkv = (const float*)d_in[1];
  const float* b_qkv = (const float*)d_in[2];
  const float* w_out = (const float*)d_in[3];
  const float* b_out = (const float*)d_in[4];

  char* ws = (char*)d_ws;
  size_t off = 0;
  auto alloc = [&](size_t bytes) -> void* {
    void* p = ws + off;
    off = (off + bytes + 255) & ~(size_t)255;
    return p;
  };
  unsigned short* xb    = (unsigned short*)alloc((size_t)B_ * S_ * H_ * 2);
  unsigned short* wqkvT = (unsigned short*)alloc((size_t)3 * H_ * H_ * 2);
  unsigned short* woutT = (unsigned short*)alloc((size_t)H_ * H_ * 2);
  unsigned short* qkv   = (unsigned short*)alloc((size_t)B_ * S_ * 3 * H_ * 2);
  unsigned short* ao    = (unsigned short*)alloc((size_t)B_ * S_ * H_ * 2);
  unsigned short* vtb   = (unsigned short*)alloc((size_t)B_ * NH_ * HD_ * S_ * 2);

  // merged prologue: cast x (8192 blocks) + transpose w_qkv (3072) + w_out (1024)
  k_prep<<<8192 + 3072 + 1024, 256, 0, stream>>>(x, w_qkv, w_out, xb, wqkvT, woutT);

  // QKV projection (BK=64, single launch); V columns go transposed into vtb
  k_gemm_bt64<true ><<<dim3(3 * H_ / 128, B_ * S_ / 128), 256, 0, stream>>>(
      xb, wqkvT, b_qkv, qkv, vtb, B_ * S_, 3 * H_, H_);

  k_attn<<<(S_ / 128) * 64, 256, 0, stream>>>(qkv, vtb, ao);

  // output projection: BK=64 variant
  k_gemm_bt64<false><<<dim3(H_ / 128, B_ * S_ / 128), 256, 0, stream>>>(
      ao, woutT, b_out, (float*)d_out, nullptr, B_ * S_, H_, H_);
}

// Round 11
// 243.294 us; speedup vs baseline: 1.1058x; 1.1058x over previous
//
#include <hip/hip_runtime.h>
#include <hip/hip_bf16.h>
#include <cstdint>

#define B_  4
#define S_  2048
#define H_  1024
#define NH_ 16
#define HD_ 64

using short8  = __attribute__((ext_vector_type(8))) short;
using floatx4 = __attribute__((ext_vector_type(4))) float;

__device__ __forceinline__ unsigned short f2b(float f) {
  union { float f; unsigned int u; } x; x.f = f;
  unsigned int r = x.u + 0x7fffu + ((x.u >> 16) & 1u);
  return (unsigned short)(r >> 16);
}
__device__ __forceinline__ unsigned short f2b_fast(float f) {
  union { float f; unsigned int u; } x; x.f = f;
  return (unsigned short)((x.u + 0x8000u) >> 16);
}
__device__ __forceinline__ unsigned int pack2(float a, float b) {
  return (unsigned int)f2b(a) | ((unsigned int)f2b(b) << 16);
}

// async global->LDS, 16B per lane. lds dest = wave-uniform base + lane*16.
__device__ __forceinline__ void async16(void* lds, const void* g) {
  __builtin_amdgcn_global_load_lds(
      (const __attribute__((address_space(1))) unsigned int*)g,
      (__attribute__((address_space(3))) unsigned int*)lds, 16, 0, 0);
}

// ---------- merged prologue: cast x + transpose both weights ----------
// qk_scale: fold attn's 1/sqrt(HD)=0.125 into Q weight columns (c<1024).
// Exact power-of-2 scale -> bf16 exponent shift only -> bit-identical attn.
__device__ __forceinline__ void transpose_tile(const float* __restrict__ in,
                                               unsigned short* __restrict__ out,
                                               int R, int C, int c0, int r0,
                                               bool qk_scale) {
  __shared__ float tile[32][33];
  int tx = threadIdx.x & 31, ty = threadIdx.x >> 5;  // 32 x 8
  for (int i = 0; i < 4; i++) {
    int r = r0 + ty + i * 8;
    tile[ty + i * 8][tx] = in[(size_t)r * C + c0 + tx];
  }
  __syncthreads();
  for (int i = 0; i < 4; i++) {
    int c = c0 + ty + i * 8;
    float s = (qk_scale && c < 1024) ? 0.125f : 1.0f;
    out[(size_t)c * R + r0 + tx] = f2b(tile[tx][ty + i * 8] * s);
  }
}

__global__ void k_prep(const float* __restrict__ x, const float* __restrict__ w_qkv,
                       const float* __restrict__ w_out,
                       unsigned short* __restrict__ xb, unsigned short* __restrict__ wqkvT,
                       unsigned short* __restrict__ woutT) {
  int bx = blockIdx.x;
  if (bx < 8192) {                       // cast x: 8192 blocks * 256 thr * 4 elems
    int i = (bx * 256 + threadIdx.x) * 4;
    float4 v = *(const float4*)(x + i);
    ushort4 o;
    o.x = f2b(v.x); o.y = f2b(v.y); o.z = f2b(v.z); o.w = f2b(v.w);
    *(ushort4*)(xb + i) = o;
  } else if (bx < 8192 + 3072) {         // w_qkv [1024][3072] -> [3072][1024]
    int t = bx - 8192;
    transpose_tile(w_qkv, wqkvT, H_, 3 * H_, (t % 96) * 32, (t / 96) * 32, true);
  } else {                               // w_out [1024][1024] -> [1024][1024]^T
    int t = bx - 8192 - 3072;
    transpose_tile(w_out, woutT, H_, H_, (t & 31) * 32, (t >> 5) * 32, false);
  }
}

// ---------- GEMM: 128x128 tile, BK=64, double-buffered (64 KB LDS) ----------
// Verified rounds 5/6: 81.5 -> 69.2 us vs BK=32 (halves barrier+drain events).
template <bool OUT_BF16>
__global__ __launch_bounds__(256, 2) void k_gemm_bt64(
    const unsigned short* __restrict__ A,   // [M][K] bf16
    const unsigned short* __restrict__ BT,  // [N][K] bf16
    const float* __restrict__ bias,         // [N]
    void* __restrict__ Cout,
    unsigned short* __restrict__ vt,        // V-transposed out (OUT_BF16 only)
    int M, int N, int K) {
  __shared__ __align__(16) unsigned short As[2][128 * 64];
  __shared__ __align__(16) unsigned short Bs[2][128 * 64];
  const int tid  = threadIdx.x;
  const int lane = tid & 63, wave = tid >> 6;
  const int quad = lane >> 4, l16 = lane & 15;
  const int wm = wave >> 1, wn = wave & 1;
  const int m0 = blockIdx.y * 128, n0 = blockIdx.x * 128;

  floatx4 acc[4][4];
#pragma unroll
  for (int mt = 0; mt < 4; mt++)
#pragma unroll
    for (int nt = 0; nt < 4; nt++)
      acc[mt][nt] = (floatx4){0.f, 0.f, 0.f, 0.f};

  // 1024 chunks (16B) per array: row = c>>3 (128 rows), slot = c&7,
  // pre-swizzled global source c8 = slot ^ (row&7).
  auto stage = [&](int k0, int bufi) {
#pragma unroll
    for (int j = 0; j < 4; j++) {
      int c = j * 256 + tid;
      int row = c >> 3, c8 = (c & 7) ^ (row & 7);
      async16(&As[bufi][c * 8], &A[(size_t)(m0 + row) * K + k0 + c8 * 8]);
    }
#pragma unroll
    for (int j = 0; j < 4; j++) {
      int c = j * 256 + tid;
      int row = c >> 3, c8 = (c & 7) ^ (row & 7);
      async16(&Bs[bufi][c * 8], &BT[(size_t)(n0 + row) * K + k0 + c8 * 8]);
    }
  };

  stage(0, 0);
  int it = 0;
  for (int k0 = 0; k0 < K; k0 += 64, it++) {
    const int cur = it & 1;
    __syncthreads();                          // buf[cur] ready (barrier drains vmcnt)
    if (k0 + 64 < K) stage(k0 + 64, cur ^ 1); // prefetch, drained at NEXT barrier
    short8 af[4][2], bq[4][2];
#pragma unroll
    for (int t = 0; t < 4; t++) {
      int ra = wm * 64 + t * 16 + l16;
      int rb = wn * 64 + t * 16 + l16;
#pragma unroll
      for (int ks = 0; ks < 2; ks++) {
        af[t][ks] = *(const short8*)&As[cur][(ra * 8 + ((ks * 4 + quad) ^ (ra & 7))) * 8];
        bq[t][ks] = *(const short8*)&Bs[cur][(rb * 8 + ((ks * 4 + quad) ^ (rb & 7))) * 8];
      }
    }
#pragma unroll
    for (int ks = 0; ks < 2; ks++)
#pragma unroll
      for (int mt = 0; mt < 4; mt++)
#pragma unroll
        for (int nt = 0; nt < 4; nt++)
          acc[mt][nt] = __builtin_amdgcn_mfma_f32_16x16x32_bf16(af[mt][ks], bq[nt][ks], acc[mt][nt], 0, 0, 0);
  }

  if (OUT_BF16 && n0 >= 2048) {
#pragma unroll
    for (int mt = 0; mt < 4; mt++) {
      int row0 = m0 + wm * 64 + mt * 16 + quad * 4;
      int b = row0 >> 11, s = row0 & 2047;
#pragma unroll
      for (int nt = 0; nt < 4; nt++) {
        int col = n0 + wn * 64 + nt * 16 + l16;
        float bv = bias[col];
        uint2 u;
        u.x = pack2(acc[mt][nt][0] + bv, acc[mt][nt][1] + bv);
        u.y = pack2(acc[mt][nt][2] + bv, acc[mt][nt][3] + bv);
        *(uint2*)&vt[(size_t)(b * 1024 + (col - 2048)) * S_ + s] = u;
      }
    }
  } else {
#pragma unroll
    for (int mt = 0; mt < 4; mt++) {
      int row = m0 + wm * 64 + mt * 16 + quad * 4;
#pragma unroll
      for (int nt = 0; nt < 4; nt++) {
        int col = n0 + wn * 64 + nt * 16 + l16;
        float bv = bias[col];
        if (OUT_BF16 && col < 1024) bv *= 0.125f;   // Q bias follows the Q-weight scale
#pragma unroll
        for (int r = 0; r < 4; r++) {
          float v = acc[mt][nt][r] + bv;
          if (OUT_BF16) ((unsigned short*)Cout)[(size_t)(row + r) * N + col] = f2b(v);
          else          ((float*)Cout)[(size_t)(row + r) * N + col] = v;
        }
      }
    }
  }
}

// ---------- flash attention (causal), S^T layout, 40 KB LDS ----------
// Q pre-scaled by 0.125 in the weights -> exp(z) directly (bit-identical).
// Round-11: restored to the verified round-6 configuration (session best,
// 243.5 us). Attn experiment ledger, all refuted by counters: setprio (-8us,
// lockstep waves), perm16 qt remap (-14us, block->CU map not observable),
// per-g P split (-3us, 40->48KB LDS cost a residency slot), inline-asm
// cvt_pk_bf16 (-25us, m240 confirmed: asm pins VGPRs, breaks co-scheduling).
// The f2b_fast pack + single 2KB P buffer + long-first qt IS the optimum
// of everything tried for this structure.
__global__ __launch_bounds__(256, 3) void k_attn(
    const unsigned short* __restrict__ qkv,  // [B*S][3H] bf16 (Q,K valid)
    const unsigned short* __restrict__ vt,   // [B*NH*HD][S] bf16
    unsigned short* __restrict__ outb) {     // [B*S][H] bf16
  __shared__ __align__(16) unsigned short Ks [2][64 * 64];  // [kv][hd] swizzled
  __shared__ __align__(16) unsigned short VTs[2][64 * 64];  // [hd][kv] swizzled
  __shared__ __align__(16) unsigned short Ps[4][16 * 64];   // per-wave [q][kv] swizzled

  const int tid  = threadIdx.x;
  const int lane = tid & 63, w = tid >> 6;
  const int quad = lane >> 4, l16 = lane & 15;
  const int qt = (S_ / 128 - 1) - (blockIdx.x >> 6);  // long blocks dispatch first
  const int bh = blockIdx.x & 63;
  const int b = bh >> 4, h = bh & 15;
  const int qwv = qt * 128 + w * 32;
  const int wv2 = w & 1;

  // Q B-fragments (S^T = K * Q^T): B[k=d][n=q], lane n=l16, k=quad*8+j
  short8 qf[2][2];
  for (int g = 0; g < 2; g++)
    for (int kh = 0; kh < 2; kh++)
      qf[g][kh] = *(const short8*)&qkv[(size_t)(b * S_ + qwv + g * 16 + l16) * (3 * H_)
                                       + h * HD_ + kh * 32 + quad * 8];

  floatx4 oacc[2][4];
  float lsum[2] = {0.f, 0.f};
  for (int g = 0; g < 2; g++)
    for (int ct = 0; ct < 4; ct++) oacc[g][ct] = (floatx4){0.f, 0.f, 0.f, 0.f};

  auto stage = [&](int kt, int bufi) {
    if (w < 2) {
      for (int j = 0; j < 4; j++) {
        int c = wv2 * 256 + j * 64 + lane;  // 0..511
        int row = c >> 3, c8 = (c & 7) ^ (row & 7);
        async16(&Ks[bufi][c * 8],
                &qkv[(size_t)(b * S_ + kt * 64 + row) * (3 * H_) + H_ + h * HD_ + c8 * 8]);
      }
    } else {
      for (int j = 0; j < 4; j++) {
        int c = wv2 * 256 + j * 64 + lane;
        int row = c >> 3, c8 = (c & 7) ^ (row & 7);
        async16(&VTs[bufi][c * 8],
                &vt[(size_t)(bh * HD_ + row) * S_ + kt * 64 + c8 * 8]);
      }
    }
  };

  unsigned short* Pw = &Ps[w][0];

  const int ktmax = 2 * qt + 1;
  stage(0, 0);
  for (int kt = 0; kt <= ktmax; kt++) {
    const int cur = kt & 1;
    __syncthreads();                          // buf[cur] visible; prev reads done
    if (kt < ktmax) stage(kt + 1, cur ^ 1);   // prefetch, hidden behind compute

    if (kt * 64 <= qwv + 31) {
      const bool need_mask = (kt * 64 + 63 > qwv);

      // V A-fragments: A[m=d][k=kv]
      short8 vf[4][2];
      for (int ct = 0; ct < 4; ct++)
        for (int kh = 0; kh < 2; kh++) {
          int vrow = ct * 16 + l16;
          vf[ct][kh] = *(const short8*)&VTs[cur][(vrow * 8 + ((kh * 4 + quad) ^ (vrow & 7))) * 8];
        }

      // S^T = K Q^T -> p (packed into regs)
      uint2 pk[2][4];
      for (int ct = 0; ct < 4; ct++) {
        int krow = ct * 16 + l16;
        short8 kf0 = *(const short8*)&Ks[cur][(krow * 8 + ((0 + quad) ^ (krow & 7))) * 8];
        short8 kf1 = *(const short8*)&Ks[cur][(krow * 8 + ((4 + quad) ^ (krow & 7))) * 8];
        for (int g = 0; g < 2; g++) {
          floatx4 z = (floatx4){0.f, 0.f, 0.f, 0.f};
          z = __builtin_amdgcn_mfma_f32_16x16x32_bf16(kf0, qf[g][0], z, 0, 0, 0);
          z = __builtin_amdgcn_mfma_f32_16x16x32_bf16(kf1, qf[g][1], z, 0, 0, 0);
          // lane: q = qwv+g*16+l16 fixed; kv = kt*64+ct*16+quad*4+r
          float p[4];
          if (need_mask) {
            int kvb = kt * 64 + ct * 16 + quad * 4;
            int q = qwv + g * 16 + l16;
            for (int r = 0; r < 4; r++)
              p[r] = (kvb + r <= q) ? __expf(z[r]) : 0.f;
          } else {
            for (int r = 0; r < 4; r++) p[r] = __expf(z[r]);
          }
          lsum[g] += (p[0] + p[1]) + (p[2] + p[3]);
          pk[g][ct].x = (unsigned int)f2b_fast(p[0]) | ((unsigned int)f2b_fast(p[1]) << 16);
          pk[g][ct].y = (unsigned int)f2b_fast(p[2]) | ((unsigned int)f2b_fast(p[3]) << 16);
        }
      }

      // per-g: P round-trip through 2 KB swizzled buffer, then PV MFMAs.
      // (DS ops in-order per wave -> WAR-safe reuse across g)
      for (int g = 0; g < 2; g++) {
        for (int ct = 0; ct < 4; ct++) {
          int slot = (ct * 2 + (quad >> 1)) ^ (l16 & 7);
          *(uint2*)&Pw[l16 * 64 + slot * 8 + (quad & 1) * 4] = pk[g][ct];
        }
        for (int kh = 0; kh < 2; kh++) {
          short8 pf = *(const short8*)&Pw[l16 * 64 + ((kh * 4 + quad) ^ (l16 & 7)) * 8];
          for (int ct = 0; ct < 4; ct++)
            oacc[g][ct] = __builtin_amdgcn_mfma_f32_16x16x32_bf16(vf[ct][kh], pf, oacc[g][ct], 0, 0, 0);
        }
      }
    }
  }

  // finish row sums: reduce across quads (lanes sharing l16 share q)
  for (int g = 0; g < 2; g++) {
    lsum[g] += __shfl_xor(lsum[g], 16);
    lsum[g] += __shfl_xor(lsum[g], 32);
  }

  // epilogue: lane holds q=l16 fixed, d=ct*16+quad*4+r -> packed 8B stores
  for (int g = 0; g < 2; g++) {
    float inv = 1.0f / lsum[g];
    int q = qwv + g * 16 + l16;
    for (int ct = 0; ct < 4; ct++) {
      uint2 u;
      u.x = pack2(oacc[g][ct][0] * inv, oacc[g][ct][1] * inv);
      u.y = pack2(oacc[g][ct][2] * inv, oacc[g][ct][3] * inv);
      *(uint2*)&outb[(size_t)(b * S_ + q) * H_ + h * HD_ + ct * 16 + quad * 4] = u;
    }
  }
}

extern "C" void kernel_launch(void* const* d_in, const int* in_sizes, int n_in,
                              void* d_out, int out_size, void* d_ws, size_t ws_size,
                              hipStream_t stream) {
  const float* x     = (const float*)d_in[0];
  const float* w_qkv = (const float*)d_in[1];
  const float* b_qkv = (const float*)d_in[2];
  const float* w_out = (const float*)d_in[3];
  const float* b_out = (const float*)d_in[4];

  char* ws = (char*)d_ws;
  size_t off = 0;
  auto alloc = [&](size_t bytes) -> void* {
    void* p = ws + off;
    off = (off + bytes + 255) & ~(size_t)255;
    return p;
  };
  unsigned short* xb    = (unsigned short*)alloc((size_t)B_ * S_ * H_ * 2);
  unsigned short* wqkvT = (unsigned short*)alloc((size_t)3 * H_ * H_ * 2);
  unsigned short* woutT = (unsigned short*)alloc((size_t)H_ * H_ * 2);
  unsigned short* qkv   = (unsigned short*)alloc((size_t)B_ * S_ * 3 * H_ * 2);
  unsigned short* ao    = (unsigned short*)alloc((size_t)B_ * S_ * H_ * 2);
  unsigned short* vtb   = (unsigned short*)alloc((size_t)B_ * NH_ * HD_ * S_ * 2);

  // merged prologue: cast x (8192 blocks) + transpose w_qkv (3072) + w_out (1024)
  k_prep<<<8192 + 3072 + 1024, 256, 0, stream>>>(x, w_qkv, w_out, xb, wqkvT, woutT);

  // QKV projection (BK=64); V columns go transposed straight into vtb
  k_gemm_bt64<true ><<<dim3(3 * H_ / 128, B_ * S_ / 128), 256, 0, stream>>>(
      xb, wqkvT, b_qkv, qkv, vtb, B_ * S_, 3 * H_, H_);

  k_attn<<<(S_ / 128) * 64, 256, 0, stream>>>(qkv, vtb, ao);

  // output projection: BK=64 variant
  k_gemm_bt64<false><<<dim3(H_ / 128, B_ * S_ / 128), 256, 0, stream>>>(
      ao, woutT, b_out, (float*)d_out, nullptr, B_ * S_, H_, H_);
}

// Round 12
// 239.537 us; speedup vs baseline: 1.1231x; 1.0157x over previous
//
#include <hip/hip_runtime.h>
#include <hip/hip_bf16.h>
#include <cstdint>

#define B_  4
#define S_  2048
#define H_  1024
#define NH_ 16
#define HD_ 64

using short8  = __attribute__((ext_vector_type(8))) short;
using floatx4 = __attribute__((ext_vector_type(4))) float;

__device__ __forceinline__ unsigned short f2b(float f) {
  union { float f; unsigned int u; } x; x.f = f;
  unsigned int r = x.u + 0x7fffu + ((x.u >> 16) & 1u);
  return (unsigned short)(r >> 16);
}
__device__ __forceinline__ unsigned short f2b_fast(float f) {
  union { float f; unsigned int u; } x; x.f = f;
  return (unsigned short)((x.u + 0x8000u) >> 16);
}
__device__ __forceinline__ unsigned int pack2(float a, float b) {
  return (unsigned int)f2b(a) | ((unsigned int)f2b(b) << 16);
}

// async global->LDS, 16B per lane. lds dest = wave-uniform base + lane*16.
__device__ __forceinline__ void async16(void* lds, const void* g) {
  __builtin_amdgcn_global_load_lds(
      (const __attribute__((address_space(1))) unsigned int*)g,
      (__attribute__((address_space(3))) unsigned int*)lds, 16, 0, 0);
}

// ---------- prologue: cast x + transpose both weights (BW-optimized r12) ----
// Old prep: 12288 blocks, 32x32 tiles, SCALAR 2B stores (64B/wave-inst) --
// inferred ~60us from the serialized-stream budget. New: 64x64 f32 tiles,
// coalesced 256B/inst loads, ushort4 (8B/lane) stores; x-cast via strided
// float4. Same f2b rounding + f32-domain 0.125 Q-fold -> bit-identical.
__device__ __forceinline__ void transpose64(const float* __restrict__ in,
                                            unsigned short* __restrict__ out,
                                            int R, int C, int c0, int r0,
                                            bool qk_scale) {
  __shared__ float tile[64][65];
  int tx = threadIdx.x & 63, ty = threadIdx.x >> 6;        // 64 x 4
#pragma unroll
  for (int i = 0; i < 16; i++) {
    int row = i * 4 + ty;
    tile[row][tx] = in[(size_t)(r0 + row) * C + c0 + tx];  // 256B/wave-inst
  }
  __syncthreads();
  int tx16 = threadIdx.x & 15, cy = threadIdx.x >> 4;      // 16 x 16
#pragma unroll
  for (int i = 0; i < 4; i++) {
    int c = i * 16 + cy;
    float s = (qk_scale && (c0 + c) < 1024) ? 0.125f : 1.0f;
    ushort4 o;
    o.x = f2b(tile[tx16 * 4 + 0][c] * s);
    o.y = f2b(tile[tx16 * 4 + 1][c] * s);
    o.z = f2b(tile[tx16 * 4 + 2][c] * s);
    o.w = f2b(tile[tx16 * 4 + 3][c] * s);                  // 2-way LDS alias: free
    *(ushort4*)&out[(size_t)(c0 + c) * R + r0 + tx16 * 4] = o;  // 8B/lane store
  }
}

__global__ void k_prep(const float* __restrict__ x, const float* __restrict__ w_qkv,
                       const float* __restrict__ w_out,
                       unsigned short* __restrict__ xb, unsigned short* __restrict__ wqkvT,
                       unsigned short* __restrict__ woutT) {
  int bx = blockIdx.x, tid = threadIdx.x;
  if (bx < 2048) {                        // cast x: 2048 blk * 256 thr * 4 * float4
    size_t base = ((size_t)bx * 256 + tid) * 4;
    const size_t stride = (size_t)2048 * 256 * 4;   // 2.097M floats
#pragma unroll
    for (int i = 0; i < 4; i++) {
      size_t idx = base + (size_t)i * stride;       // exactly covers 8.389M floats
      float4 v = *(const float4*)(x + idx);
      ushort4 o;
      o.x = f2b(v.x); o.y = f2b(v.y); o.z = f2b(v.z); o.w = f2b(v.w);
      *(ushort4*)(xb + idx) = o;
    }
  } else if (bx < 2048 + 768) {           // w_qkv [1024][3072] -> [3072][1024]
    int t = bx - 2048;                    // 16 r-tiles x 48 c-tiles
    transpose64(w_qkv, wqkvT, H_, 3 * H_, (t % 48) * 64, (t / 48) * 64, true);
  } else {                                // w_out [1024][1024] -> transposed
    int t = bx - 2048 - 768;              // 16 x 16
    transpose64(w_out, woutT, H_, H_, (t & 15) * 64, (t >> 4) * 64, false);
  }
}

// ---------- GEMM: 128x128 tile, BK=64, double-buffered (64 KB LDS) ----------
// Verified rounds 5/6: 81.5 -> 69.2 us vs BK=32 (halves barrier+drain events).
template <bool OUT_BF16>
__global__ __launch_bounds__(256, 2) void k_gemm_bt64(
    const unsigned short* __restrict__ A,   // [M][K] bf16
    const unsigned short* __restrict__ BT,  // [N][K] bf16
    const float* __restrict__ bias,         // [N]
    void* __restrict__ Cout,
    unsigned short* __restrict__ vt,        // V-transposed out (OUT_BF16 only)
    int M, int N, int K) {
  __shared__ __align__(16) unsigned short As[2][128 * 64];
  __shared__ __align__(16) unsigned short Bs[2][128 * 64];
  const int tid  = threadIdx.x;
  const int lane = tid & 63, wave = tid >> 6;
  const int quad = lane >> 4, l16 = lane & 15;
  const int wm = wave >> 1, wn = wave & 1;
  const int m0 = blockIdx.y * 128, n0 = blockIdx.x * 128;

  floatx4 acc[4][4];
#pragma unroll
  for (int mt = 0; mt < 4; mt++)
#pragma unroll
    for (int nt = 0; nt < 4; nt++)
      acc[mt][nt] = (floatx4){0.f, 0.f, 0.f, 0.f};

  // 1024 chunks (16B) per array: row = c>>3 (128 rows), slot = c&7,
  // pre-swizzled global source c8 = slot ^ (row&7).
  auto stage = [&](int k0, int bufi) {
#pragma unroll
    for (int j = 0; j < 4; j++) {
      int c = j * 256 + tid;
      int row = c >> 3, c8 = (c & 7) ^ (row & 7);
      async16(&As[bufi][c * 8], &A[(size_t)(m0 + row) * K + k0 + c8 * 8]);
    }
#pragma unroll
    for (int j = 0; j < 4; j++) {
      int c = j * 256 + tid;
      int row = c >> 3, c8 = (c & 7) ^ (row & 7);
      async16(&Bs[bufi][c * 8], &BT[(size_t)(n0 + row) * K + k0 + c8 * 8]);
    }
  };

  stage(0, 0);
  int it = 0;
  for (int k0 = 0; k0 < K; k0 += 64, it++) {
    const int cur = it & 1;
    __syncthreads();                          // buf[cur] ready (barrier drains vmcnt)
    if (k0 + 64 < K) stage(k0 + 64, cur ^ 1); // prefetch, drained at NEXT barrier
    short8 af[4][2], bq[4][2];
#pragma unroll
    for (int t = 0; t < 4; t++) {
      int ra = wm * 64 + t * 16 + l16;
      int rb = wn * 64 + t * 16 + l16;
#pragma unroll
      for (int ks = 0; ks < 2; ks++) {
        af[t][ks] = *(const short8*)&As[cur][(ra * 8 + ((ks * 4 + quad) ^ (ra & 7))) * 8];
        bq[t][ks] = *(const short8*)&Bs[cur][(rb * 8 + ((ks * 4 + quad) ^ (rb & 7))) * 8];
      }
    }
#pragma unroll
    for (int ks = 0; ks < 2; ks++)
#pragma unroll
      for (int mt = 0; mt < 4; mt++)
#pragma unroll
        for (int nt = 0; nt < 4; nt++)
          acc[mt][nt] = __builtin_amdgcn_mfma_f32_16x16x32_bf16(af[mt][ks], bq[nt][ks], acc[mt][nt], 0, 0, 0);
  }

  if (OUT_BF16 && n0 >= 2048) {
#pragma unroll
    for (int mt = 0; mt < 4; mt++) {
      int row0 = m0 + wm * 64 + mt * 16 + quad * 4;
      int b = row0 >> 11, s = row0 & 2047;
#pragma unroll
      for (int nt = 0; nt < 4; nt++) {
        int col = n0 + wn * 64 + nt * 16 + l16;
        float bv = bias[col];
        uint2 u;
        u.x = pack2(acc[mt][nt][0] + bv, acc[mt][nt][1] + bv);
        u.y = pack2(acc[mt][nt][2] + bv, acc[mt][nt][3] + bv);
        *(uint2*)&vt[(size_t)(b * 1024 + (col - 2048)) * S_ + s] = u;
      }
    }
  } else {
#pragma unroll
    for (int mt = 0; mt < 4; mt++) {
      int row = m0 + wm * 64 + mt * 16 + quad * 4;
#pragma unroll
      for (int nt = 0; nt < 4; nt++) {
        int col = n0 + wn * 64 + nt * 16 + l16;
        float bv = bias[col];
        if (OUT_BF16 && col < 1024) bv *= 0.125f;   // Q bias follows the Q-weight scale
#pragma unroll
        for (int r = 0; r < 4; r++) {
          float v = acc[mt][nt][r] + bv;
          if (OUT_BF16) ((unsigned short*)Cout)[(size_t)(row + r) * N + col] = f2b(v);
          else          ((float*)Cout)[(size_t)(row + r) * N + col] = v;
        }
      }
    }
  }
}

// ---------- flash attention (causal), S^T layout, 40 KB LDS ----------
// Verified round-6 configuration (66.5 us). Ledger of refuted edits: setprio
// (-8), perm16 (-14), per-g P split (-3, occupancy), inline cvt_pk (-25).
__global__ __launch_bounds__(256, 3) void k_attn(
    const unsigned short* __restrict__ qkv,  // [B*S][3H] bf16 (Q,K valid)
    const unsigned short* __restrict__ vt,   // [B*NH*HD][S] bf16
    unsigned short* __restrict__ outb) {     // [B*S][H] bf16
  __shared__ __align__(16) unsigned short Ks [2][64 * 64];  // [kv][hd] swizzled
  __shared__ __align__(16) unsigned short VTs[2][64 * 64];  // [hd][kv] swizzled
  __shared__ __align__(16) unsigned short Ps[4][16 * 64];   // per-wave [q][kv] swizzled

  const int tid  = threadIdx.x;
  const int lane = tid & 63, w = tid >> 6;
  const int quad = lane >> 4, l16 = lane & 15;
  const int qt = (S_ / 128 - 1) - (blockIdx.x >> 6);  // long blocks dispatch first
  const int bh = blockIdx.x & 63;
  const int b = bh >> 4, h = bh & 15;
  const int qwv = qt * 128 + w * 32;
  const int wv2 = w & 1;

  // Q B-fragments (S^T = K * Q^T): B[k=d][n=q], lane n=l16, k=quad*8+j
  short8 qf[2][2];
  for (int g = 0; g < 2; g++)
    for (int kh = 0; kh < 2; kh++)
      qf[g][kh] = *(const short8*)&qkv[(size_t)(b * S_ + qwv + g * 16 + l16) * (3 * H_)
                                       + h * HD_ + kh * 32 + quad * 8];

  floatx4 oacc[2][4];
  float lsum[2] = {0.f, 0.f};
  for (int g = 0; g < 2; g++)
    for (int ct = 0; ct < 4; ct++) oacc[g][ct] = (floatx4){0.f, 0.f, 0.f, 0.f};

  auto stage = [&](int kt, int bufi) {
    if (w < 2) {
      for (int j = 0; j < 4; j++) {
        int c = wv2 * 256 + j * 64 + lane;  // 0..511
        int row = c >> 3, c8 = (c & 7) ^ (row & 7);
        async16(&Ks[bufi][c * 8],
                &qkv[(size_t)(b * S_ + kt * 64 + row) * (3 * H_) + H_ + h * HD_ + c8 * 8]);
      }
    } else {
      for (int j = 0; j < 4; j++) {
        int c = wv2 * 256 + j * 64 + lane;
        int row = c >> 3, c8 = (c & 7) ^ (row & 7);
        async16(&VTs[bufi][c * 8],
                &vt[(size_t)(bh * HD_ + row) * S_ + kt * 64 + c8 * 8]);
      }
    }
  };

  unsigned short* Pw = &Ps[w][0];

  const int ktmax = 2 * qt + 1;
  stage(0, 0);
  for (int kt = 0; kt <= ktmax; kt++) {
    const int cur = kt & 1;
    __syncthreads();                          // buf[cur] visible; prev reads done
    if (kt < ktmax) stage(kt + 1, cur ^ 1);   // prefetch, hidden behind compute

    if (kt * 64 <= qwv + 31) {
      const bool need_mask = (kt * 64 + 63 > qwv);

      // V A-fragments: A[m=d][k=kv]
      short8 vf[4][2];
      for (int ct = 0; ct < 4; ct++)
        for (int kh = 0; kh < 2; kh++) {
          int vrow = ct * 16 + l16;
          vf[ct][kh] = *(const short8*)&VTs[cur][(vrow * 8 + ((kh * 4 + quad) ^ (vrow & 7))) * 8];
        }

      // S^T = K Q^T -> p (packed into regs)
      uint2 pk[2][4];
      for (int ct = 0; ct < 4; ct++) {
        int krow = ct * 16 + l16;
        short8 kf0 = *(const short8*)&Ks[cur][(krow * 8 + ((0 + quad) ^ (krow & 7))) * 8];
        short8 kf1 = *(const short8*)&Ks[cur][(krow * 8 + ((4 + quad) ^ (krow & 7))) * 8];
        for (int g = 0; g < 2; g++) {
          floatx4 z = (floatx4){0.f, 0.f, 0.f, 0.f};
          z = __builtin_amdgcn_mfma_f32_16x16x32_bf16(kf0, qf[g][0], z, 0, 0, 0);
          z = __builtin_amdgcn_mfma_f32_16x16x32_bf16(kf1, qf[g][1], z, 0, 0, 0);
          // lane: q = qwv+g*16+l16 fixed; kv = kt*64+ct*16+quad*4+r
          float p[4];
          if (need_mask) {
            int kvb = kt * 64 + ct * 16 + quad * 4;
            int q = qwv + g * 16 + l16;
            for (int r = 0; r < 4; r++)
              p[r] = (kvb + r <= q) ? __expf(z[r]) : 0.f;
          } else {
            for (int r = 0; r < 4; r++) p[r] = __expf(z[r]);
          }
          lsum[g] += (p[0] + p[1]) + (p[2] + p[3]);
          pk[g][ct].x = (unsigned int)f2b_fast(p[0]) | ((unsigned int)f2b_fast(p[1]) << 16);
          pk[g][ct].y = (unsigned int)f2b_fast(p[2]) | ((unsigned int)f2b_fast(p[3]) << 16);
        }
      }

      // per-g: P round-trip through 2 KB swizzled buffer, then PV MFMAs.
      // (DS ops in-order per wave -> WAR-safe reuse across g)
      for (int g = 0; g < 2; g++) {
        for (int ct = 0; ct < 4; ct++) {
          int slot = (ct * 2 + (quad >> 1)) ^ (l16 & 7);
          *(uint2*)&Pw[l16 * 64 + slot * 8 + (quad & 1) * 4] = pk[g][ct];
        }
        for (int kh = 0; kh < 2; kh++) {
          short8 pf = *(const short8*)&Pw[l16 * 64 + ((kh * 4 + quad) ^ (l16 & 7)) * 8];
          for (int ct = 0; ct < 4; ct++)
            oacc[g][ct] = __builtin_amdgcn_mfma_f32_16x16x32_bf16(vf[ct][kh], pf, oacc[g][ct], 0, 0, 0);
        }
      }
    }
  }

  // finish row sums: reduce across quads (lanes sharing l16 share q)
  for (int g = 0; g < 2; g++) {
    lsum[g] += __shfl_xor(lsum[g], 16);
    lsum[g] += __shfl_xor(lsum[g], 32);
  }

  // epilogue: lane holds q=l16 fixed, d=ct*16+quad*4+r -> packed 8B stores
  for (int g = 0; g < 2; g++) {
    float inv = 1.0f / lsum[g];
    int q = qwv + g * 16 + l16;
    for (int ct = 0; ct < 4; ct++) {
      uint2 u;
      u.x = pack2(oacc[g][ct][0] * inv, oacc[g][ct][1] * inv);
      u.y = pack2(oacc[g][ct][2] * inv, oacc[g][ct][3] * inv);
      *(uint2*)&outb[(size_t)(b * S_ + q) * H_ + h * HD_ + ct * 16 + quad * 4] = u;
    }
  }
}

extern "C" void kernel_launch(void* const* d_in, const int* in_sizes, int n_in,
                              void* d_out, int out_size, void* d_ws, size_t ws_size,
                              hipStream_t stream) {
  const float* x     = (const float*)d_in[0];
  const float* w_qkv = (const float*)d_in[1];
  const float* b_qkv = (const float*)d_in[2];
  const float* w_out = (const float*)d_in[3];
  const float* b_out = (const float*)d_in[4];

  char* ws = (char*)d_ws;
  size_t off = 0;
  auto alloc = [&](size_t bytes) -> void* {
    void* p = ws + off;
    off = (off + bytes + 255) & ~(size_t)255;
    return p;
  };
  unsigned short* xb    = (unsigned short*)alloc((size_t)B_ * S_ * H_ * 2);
  unsigned short* wqkvT = (unsigned short*)alloc((size_t)3 * H_ * H_ * 2);
  unsigned short* woutT = (unsigned short*)alloc((size_t)H_ * H_ * 2);
  unsigned short* qkv   = (unsigned short*)alloc((size_t)B_ * S_ * 3 * H_ * 2);
  unsigned short* ao    = (unsigned short*)alloc((size_t)B_ * S_ * H_ * 2);
  unsigned short* vtb   = (unsigned short*)alloc((size_t)B_ * NH_ * HD_ * S_ * 2);

  // BW-optimized prologue: cast x (2048) + transpose w_qkv (768) + w_out (256)
  k_prep<<<2048 + 768 + 256, 256, 0, stream>>>(x, w_qkv, w_out, xb, wqkvT, woutT);

  // QKV projection (BK=64); V columns go transposed straight into vtb
  k_gemm_bt64<true ><<<dim3(3 * H_ / 128, B_ * S_ / 128), 256, 0, stream>>>(
      xb, wqkvT, b_qkv, qkv, vtb, B_ * S_, 3 * H_, H_);

  k_attn<<<(S_ / 128) * 64, 256, 0, stream>>>(qkv, vtb, ao);

  // output projection: BK=64 variant
  k_gemm_bt64<false><<<dim3(H_ / 128, B_ * S_ / 128), 256, 0, stream>>>(
      ao, woutT, b_out, (float*)d_out, nullptr, B_ * S_, H_, H_);
}